// Round 1
// baseline (403.258 us; speedup 1.0000x reference)
//
#include <hip/hip_runtime.h>
#include <cstdint>
#include <cstddef>

typedef __bf16 bf16;
typedef __bf16 bf16x8 __attribute__((ext_vector_type(8)));
typedef __bf16 bf16x4 __attribute__((ext_vector_type(4)));
typedef float f32x4 __attribute__((ext_vector_type(4)));

#define DEVI __device__ __forceinline__

DEVI void gload_lds16(const bf16* g, bf16* l) {
    __builtin_amdgcn_global_load_lds(
        (const __attribute__((address_space(1))) void*)(const void*)g,
        (__attribute__((address_space(3))) void*)(void*)l, 16, 0, 0);
}

// ---------------- weight convert + transpose: W[K][N] f32 -> Wt[N][K] bf16 ----
__global__ void conv_t_kernel(const float* __restrict__ W, bf16* __restrict__ Wt,
                              int K, int N) {
    __shared__ float tile[64][65];
    const int tid = threadIdx.x;
    const int c  = tid & 63;
    const int r4 = tid >> 6;   // 0..3
    const int n0 = blockIdx.x * 64;
    const int k0 = blockIdx.y * 64;
#pragma unroll
    for (int r = 0; r < 64; r += 4)
        tile[r + r4][c] = W[(size_t)(k0 + r + r4) * N + n0 + c];
    __syncthreads();
#pragma unroll
    for (int r = 0; r < 64; r += 4)
        Wt[(size_t)(n0 + r + r4) * K + k0 + c] = (bf16)tile[c][r + r4];
}

// ---------------- DyT: h = gamma*tanh(alpha*x)+beta  (f32 -> bf16) -----------
__global__ void dyt_kernel(const float* __restrict__ x, const float* __restrict__ alpha,
                           const float* __restrict__ gamma, const float* __restrict__ beta,
                           bf16* __restrict__ h, int total) {
    int i4 = (blockIdx.x * 256 + threadIdx.x) * 4;
    if (i4 >= total) return;
    float a = alpha[0];
    float4 xv = *(const float4*)&x[i4];
    int c = i4 & 1023;
    float4 g  = *(const float4*)&gamma[c];
    float4 bt = *(const float4*)&beta[c];
    bf16x4 o;
    o[0] = (bf16)(g.x * tanhf(xv.x * a) + bt.x);
    o[1] = (bf16)(g.y * tanhf(xv.y * a) + bt.y);
    o[2] = (bf16)(g.z * tanhf(xv.z * a) + bt.z);
    o[3] = (bf16)(g.w * tanhf(xv.w * a) + bt.w);
    *(bf16x4*)&h[i4] = o;
}

// ---------------- GEMM: C = A[M][K] @ Wt[N][K]^T, 128x128x32, 4 waves --------
// OP 0: out_bf16 = acc + bias                         (QKV)
// OP 1: v = acc+bias+resid; out_f32 = v; out_bf16 = DyT(v)   (proj + resid + DyT)
// OP 2: out_bf16 = gelu_exact(acc + bias)             (fc)
// OP 3: out_f32 = acc + bias + resid                  (fc2 + resid -> d_out)
template<int OP>
__global__ void gemm_kernel(const bf16* __restrict__ A, const bf16* __restrict__ Wt,
                            const float* __restrict__ bias, const float* resid,
                            float* outf, bf16* outb,
                            const float* __restrict__ alpha_p,
                            const float* __restrict__ gamma,
                            const float* __restrict__ beta,
                            int M, int N, int K) {
    __shared__ bf16 As[128 * 32];
    __shared__ bf16 Bs[128 * 32];
    const int tid  = threadIdx.x;
    const int lane = tid & 63;
    const int w    = tid >> 6;
    const int wr   = w >> 1, wc = w & 1;
    const int bm = blockIdx.y * 128;
    const int bn = blockIdx.x * 128;

    f32x4 acc[4][4] = {};

    const bf16* a0 = A  + (size_t)(bm + (tid >> 2)) * K + (tid & 3) * 8;
    const bf16* a1 = a0 + (size_t)64 * K;
    const bf16* b0 = Wt + (size_t)(bn + (tid >> 2)) * K + (tid & 3) * 8;
    const bf16* b1 = b0 + (size_t)64 * K;
    bf16* lA0 = As + tid * 8;
    bf16* lA1 = As + 2048 + tid * 8;
    bf16* lB0 = Bs + tid * 8;
    bf16* lB1 = Bs + 2048 + tid * 8;

    const int arow = wr * 64 + (lane & 15);
    const int brow = wc * 64 + (lane & 15);
    const int koff = (lane >> 4) * 8;

    for (int k0 = 0; k0 < K; k0 += 32) {
        __syncthreads();
        gload_lds16(a0, lA0);
        gload_lds16(a1, lA1);
        gload_lds16(b0, lB0);
        gload_lds16(b1, lB1);
        a0 += 32; a1 += 32; b0 += 32; b1 += 32;
        __syncthreads();
        bf16x8 af[4], bfr[4];
#pragma unroll
        for (int i = 0; i < 4; i++)
            af[i] = *(const bf16x8*)&As[(arow + i * 16) * 32 + koff];
#pragma unroll
        for (int i = 0; i < 4; i++)
            bfr[i] = *(const bf16x8*)&Bs[(brow + i * 16) * 32 + koff];
#pragma unroll
        for (int i = 0; i < 4; i++)
#pragma unroll
            for (int j = 0; j < 4; j++)
                acc[i][j] = __builtin_amdgcn_mfma_f32_16x16x32_bf16(af[i], bfr[j], acc[i][j], 0, 0, 0);
    }

    const int lh = lane >> 4, lm = lane & 15;
#pragma unroll
    for (int i = 0; i < 4; i++) {
        const int row0 = bm + wr * 64 + i * 16 + lh * 4;
#pragma unroll
        for (int jf = 0; jf < 4; jf++) {
            const int col = bn + wc * 64 + jf * 16 + lm;
            const float bval = bias[col];
#pragma unroll
            for (int r = 0; r < 4; r++) {
                const int row = row0 + r;
                const size_t idx = (size_t)row * N + col;
                float v = acc[i][jf][r] + bval;
                if (OP == 0) {
                    outb[idx] = (bf16)v;
                } else if (OP == 1) {
                    v += resid[idx];
                    outf[idx] = v;
                    float hh = gamma[col] * tanhf(v * alpha_p[0]) + beta[col];
                    outb[idx] = (bf16)hh;
                } else if (OP == 2) {
                    float g = 0.5f * v * (1.0f + erff(v * 0.70710678118f));
                    outb[idx] = (bf16)g;
                } else {
                    v += resid[idx];
                    outf[idx] = v;
                }
            }
        }
    }
}

// ---------------- causal flash attention, H=16 D=64 T=2048 -------------------
// qkv: [B,T,3C] bf16 ; out: [B,T,C] bf16. 4 waves x 16 q-rows, kv tiles of 64.
__global__ void attn_kernel(const bf16* __restrict__ qkv, bf16* __restrict__ out) {
    const int bq = blockIdx.x;          // q tile (64 rows)
    const int bh = blockIdx.y;          // b*16 + h
    const int b = bh >> 4, h = bh & 15;
    const int tid = threadIdx.x, lane = tid & 63, w = tid >> 6;
    const int T = 2048;
    const size_t C3 = 3072;
    const bf16* qb = qkv + (size_t)b * T * C3 + h * 64;
    const bf16* kb = qb + 1024;
    const bf16* vb = qb + 2048;

    __shared__ bf16 Vt[64][72];         // [d][k], padded
    __shared__ bf16 Pl[4][16][72];      // per-wave P [q][k], padded

    const int q0w = bq * 64 + w * 16;
    const int lm = lane & 15;
    const int lh = lane >> 4;

    bf16x8 qf0, qf1;
    {
        size_t qoff = (size_t)(q0w + lm) * C3 + lh * 8;
        qf0 = *(const bf16x8*)&qb[qoff];
        qf1 = *(const bf16x8*)&qb[qoff + 32];
    }
    f32x4 acc[4] = {};
    float mrow[4] = {-1e30f, -1e30f, -1e30f, -1e30f};
    float lrow[4] = {0.f, 0.f, 0.f, 0.f};

    for (int kt = 0; kt <= bq; ++kt) {
        const int k0 = kt * 64;
        __syncthreads();
        {   // stage V transposed: Vt[d][k]
            const int krow = tid >> 3;
            const int dcol = (tid & 7) * 8;
#pragma unroll
            for (int r = 0; r < 2; ++r) {
                bf16x8 vv = *(const bf16x8*)&vb[(size_t)(k0 + r * 32 + krow) * C3 + dcol];
#pragma unroll
                for (int e = 0; e < 8; e++) Vt[dcol + e][r * 32 + krow] = vv[e];
            }
        }
        __syncthreads();

        // S = (Q K^T) for this wave's 16 q-rows x 64 k-cols
        f32x4 s[4];
#pragma unroll
        for (int f = 0; f < 4; ++f) {
            size_t kg = (size_t)(k0 + f * 16 + lm) * C3 + lh * 8;
            bf16x8 kf0 = *(const bf16x8*)&kb[kg];
            bf16x8 kf1 = *(const bf16x8*)&kb[kg + 32];
            f32x4 z = {};
            z = __builtin_amdgcn_mfma_f32_16x16x32_bf16(qf0, kf0, z, 0, 0, 0);
            z = __builtin_amdgcn_mfma_f32_16x16x32_bf16(qf1, kf1, z, 0, 0, 0);
            s[f] = z;
        }
        const bool diag = (kt == bq);
#pragma unroll
        for (int f = 0; f < 4; f++) {
            const int kc = k0 + f * 16 + lm;
#pragma unroll
            for (int j = 0; j < 4; j++) {
                float v = s[f][j] * 0.125f;
                if (diag && kc > q0w + lh * 4 + j) v = -1e30f;
                s[f][j] = v;
            }
        }
        // online softmax per row j (rows live in 16-lane groups)
#pragma unroll
        for (int j = 0; j < 4; j++) {
            float m = fmaxf(fmaxf(s[0][j], s[1][j]), fmaxf(s[2][j], s[3][j]));
            m = fmaxf(m, __shfl_xor(m, 1));
            m = fmaxf(m, __shfl_xor(m, 2));
            m = fmaxf(m, __shfl_xor(m, 4));
            m = fmaxf(m, __shfl_xor(m, 8));
            float mnew = fmaxf(mrow[j], m);
            float corr = __expf(mrow[j] - mnew);
            mrow[j] = mnew;
            lrow[j] *= corr;
#pragma unroll
            for (int df = 0; df < 4; df++) acc[df][j] *= corr;
            float rsum = 0.f;
#pragma unroll
            for (int f = 0; f < 4; f++) {
                float p = __expf(s[f][j] - mnew);
                s[f][j] = p;
                rsum += p;
            }
            rsum += __shfl_xor(rsum, 1);
            rsum += __shfl_xor(rsum, 2);
            rsum += __shfl_xor(rsum, 4);
            rsum += __shfl_xor(rsum, 8);
            lrow[j] += rsum;
        }
        // P -> LDS (bf16), then PV
#pragma unroll
        for (int f = 0; f < 4; f++)
#pragma unroll
            for (int j = 0; j < 4; j++)
                Pl[w][lh * 4 + j][f * 16 + lm] = (bf16)s[f][j];
#pragma unroll
        for (int kk = 0; kk < 2; kk++) {
            bf16x8 pa = *(const bf16x8*)&Pl[w][lm][kk * 32 + lh * 8];
#pragma unroll
            for (int df = 0; df < 4; df++) {
                bf16x8 vfr = *(const bf16x8*)&Vt[df * 16 + lm][kk * 32 + lh * 8];
                acc[df] = __builtin_amdgcn_mfma_f32_16x16x32_bf16(pa, vfr, acc[df], 0, 0, 0);
            }
        }
    }

    bf16* ob = out + (size_t)b * T * 1024 + h * 64;
#pragma unroll
    for (int j = 0; j < 4; j++) {
        const float inv = 1.0f / lrow[j];
        const int q = q0w + lh * 4 + j;
#pragma unroll
        for (int df = 0; df < 4; df++)
            ob[(size_t)q * 1024 + df * 16 + lm] = (bf16)(acc[df][j] * inv);
    }
}

// -----------------------------------------------------------------------------
extern "C" void kernel_launch(void* const* d_in, const int* in_sizes, int n_in,
                              void* d_out, int out_size, void* d_ws, size_t ws_size,
                              hipStream_t stream) {
    const float* x      = (const float*)d_in[0];
    const float* alpha  = (const float*)d_in[1];
    const float* gamma  = (const float*)d_in[2];
    const float* beta   = (const float*)d_in[3];
    const float* w_attn = (const float*)d_in[4];
    const float* b_attn = (const float*)d_in[5];
    const float* w_proj = (const float*)d_in[6];
    const float* b_proj = (const float*)d_in[7];
    const float* w_fc   = (const float*)d_in[8];
    const float* b_fc   = (const float*)d_in[9];
    const float* w_fc2  = (const float*)d_in[10];
    const float* b_fc2  = (const float*)d_in[11];
    float* out = (float*)d_out;

    const int M = 4096, C = 1024, F = 4096;
    char* ws = (char*)d_ws;
    bf16* wt_attn = (bf16*)ws;                        // [3C][C]   6 MB
    bf16* wt_proj = wt_attn + (size_t)3 * C * C;      // [C][C]    2 MB
    bf16* wt_fc   = wt_proj + (size_t)C * C;          // [F][C]    8 MB
    bf16* wt_fc2  = wt_fc   + (size_t)F * C;          // [C][F]    8 MB
    bf16* hbuf    = wt_fc2  + (size_t)C * F;          // [M][C]    8 MB (h, then h2)
    bf16* qkvbuf  = hbuf    + (size_t)M * C;          // [M][3C] then act [M][F] 32 MB
    bf16* aout    = qkvbuf  + (size_t)M * F;          // [M][C]    8 MB
    float* x2     = (float*)(aout + (size_t)M * C);   // [M][C]   16 MB

    dim3 blk(256);
    conv_t_kernel<<<dim3(3 * C / 64, C / 64), blk, 0, stream>>>(w_attn, wt_attn, C, 3 * C);
    conv_t_kernel<<<dim3(C / 64, C / 64),     blk, 0, stream>>>(w_proj, wt_proj, C, C);
    conv_t_kernel<<<dim3(F / 64, C / 64),     blk, 0, stream>>>(w_fc,   wt_fc,   C, F);
    conv_t_kernel<<<dim3(C / 64, F / 64),     blk, 0, stream>>>(w_fc2,  wt_fc2,  F, C);

    dyt_kernel<<<dim3(M * C / 1024), blk, 0, stream>>>(x, alpha, gamma, beta, hbuf, M * C);

    // QKV: [M][3C] = h @ w_attn
    gemm_kernel<0><<<dim3(3 * C / 128, M / 128), blk, 0, stream>>>(
        hbuf, wt_attn, b_attn, nullptr, nullptr, qkvbuf, nullptr, nullptr, nullptr, M, 3 * C, C);

    attn_kernel<<<dim3(32, 32), blk, 0, stream>>>(qkvbuf, aout);

    // proj + residual(x) -> x2 (f32) and h2 = DyT(x2) (bf16, into hbuf)
    gemm_kernel<1><<<dim3(C / 128, M / 128), blk, 0, stream>>>(
        aout, wt_proj, b_proj, x, x2, hbuf, alpha, gamma, beta, M, C, C);

    // fc + gelu -> act (reuse qkvbuf region, [M][F])
    gemm_kernel<2><<<dim3(F / 128, M / 128), blk, 0, stream>>>(
        hbuf, wt_fc, b_fc, nullptr, nullptr, qkvbuf, nullptr, nullptr, nullptr, M, F, C);

    // fc2 + residual(x2) -> d_out (f32)
    gemm_kernel<3><<<dim3(C / 128, M / 128), blk, 0, stream>>>(
        qkvbuf, wt_fc2, b_fc2, x2, out, nullptr, nullptr, nullptr, nullptr, M, C, F);
}

// Round 2
// 368.141 us; speedup vs baseline: 1.0954x; 1.0954x over previous
//
#include <hip/hip_runtime.h>
#include <cstdint>
#include <cstddef>

typedef __bf16 bf16;
typedef __bf16 bf16x8 __attribute__((ext_vector_type(8)));
typedef __bf16 bf16x4 __attribute__((ext_vector_type(4)));
typedef float f32x4 __attribute__((ext_vector_type(4)));

#define DEVI __device__ __forceinline__

DEVI void gload_lds16(const bf16* g, bf16* l) {
    __builtin_amdgcn_global_load_lds(
        (const __attribute__((address_space(1))) void*)(const void*)g,
        (__attribute__((address_space(3))) void*)(void*)l, 16, 0, 0);
}

// ---------------- weight convert + transpose: W[K][N] f32 -> Wt[N][K] bf16 ----
__global__ void conv_t_kernel(const float* __restrict__ W, bf16* __restrict__ Wt,
                              int K, int N) {
    __shared__ float tile[64][65];
    const int tid = threadIdx.x;
    const int c  = tid & 63;
    const int r4 = tid >> 6;   // 0..3
    const int n0 = blockIdx.x * 64;
    const int k0 = blockIdx.y * 64;
#pragma unroll
    for (int r = 0; r < 64; r += 4)
        tile[r + r4][c] = W[(size_t)(k0 + r + r4) * N + n0 + c];
    __syncthreads();
#pragma unroll
    for (int r = 0; r < 64; r += 4)
        Wt[(size_t)(n0 + r + r4) * K + k0 + c] = (bf16)tile[c][r + r4];
}

// ---------------- DyT: h = gamma*tanh(alpha*x)+beta  (f32 -> bf16) -----------
__global__ void dyt_kernel(const float* __restrict__ x, const float* __restrict__ alpha,
                           const float* __restrict__ gamma, const float* __restrict__ beta,
                           bf16* __restrict__ h, int total) {
    int i4 = (blockIdx.x * 256 + threadIdx.x) * 4;
    if (i4 >= total) return;
    float a = alpha[0];
    float4 xv = *(const float4*)&x[i4];
    int c = i4 & 1023;
    float4 g  = *(const float4*)&gamma[c];
    float4 bt = *(const float4*)&beta[c];
    bf16x4 o;
    o[0] = (bf16)(g.x * tanhf(xv.x * a) + bt.x);
    o[1] = (bf16)(g.y * tanhf(xv.y * a) + bt.y);
    o[2] = (bf16)(g.z * tanhf(xv.z * a) + bt.z);
    o[3] = (bf16)(g.w * tanhf(xv.w * a) + bt.w);
    *(bf16x4*)&h[i4] = o;
}

// ---------------- GEMM: C = A[M][K] @ Wt[N][K]^T, 128x128x32, 4 waves --------
// OP 0: out_bf16 = acc + bias                         (QKV)
// OP 1: v = acc+bias+resid; out_f32 = v; out_bf16 = DyT(v)   (proj + resid + DyT)
// OP 2: out_bf16 = gelu_exact(acc + bias)             (fc)
// OP 3: out_f32 = acc + bias + resid                  (fc2 + resid -> d_out)
template<int OP>
__global__ void gemm_kernel(const bf16* __restrict__ A, const bf16* __restrict__ Wt,
                            const float* __restrict__ bias, const float* resid,
                            float* outf, bf16* outb,
                            const float* __restrict__ alpha_p,
                            const float* __restrict__ gamma,
                            const float* __restrict__ beta,
                            int M, int N, int K) {
    __shared__ bf16 As[128 * 32];
    __shared__ bf16 Bs[128 * 32];
    const int tid  = threadIdx.x;
    const int lane = tid & 63;
    const int w    = tid >> 6;
    const int wr   = w >> 1, wc = w & 1;
    const int bm = blockIdx.y * 128;
    const int bn = blockIdx.x * 128;

    f32x4 acc[4][4] = {};

    const bf16* a0 = A  + (size_t)(bm + (tid >> 2)) * K + (tid & 3) * 8;
    const bf16* a1 = a0 + (size_t)64 * K;
    const bf16* b0 = Wt + (size_t)(bn + (tid >> 2)) * K + (tid & 3) * 8;
    const bf16* b1 = b0 + (size_t)64 * K;
    bf16* lA0 = As + tid * 8;
    bf16* lA1 = As + 2048 + tid * 8;
    bf16* lB0 = Bs + tid * 8;
    bf16* lB1 = Bs + 2048 + tid * 8;

    const int arow = wr * 64 + (lane & 15);
    const int brow = wc * 64 + (lane & 15);
    const int koff = (lane >> 4) * 8;

    for (int k0 = 0; k0 < K; k0 += 32) {
        __syncthreads();
        gload_lds16(a0, lA0);
        gload_lds16(a1, lA1);
        gload_lds16(b0, lB0);
        gload_lds16(b1, lB1);
        a0 += 32; a1 += 32; b0 += 32; b1 += 32;
        __syncthreads();
        bf16x8 af[4], bfr[4];
#pragma unroll
        for (int i = 0; i < 4; i++)
            af[i] = *(const bf16x8*)&As[(arow + i * 16) * 32 + koff];
#pragma unroll
        for (int i = 0; i < 4; i++)
            bfr[i] = *(const bf16x8*)&Bs[(brow + i * 16) * 32 + koff];
#pragma unroll
        for (int i = 0; i < 4; i++)
#pragma unroll
            for (int j = 0; j < 4; j++)
                acc[i][j] = __builtin_amdgcn_mfma_f32_16x16x32_bf16(af[i], bfr[j], acc[i][j], 0, 0, 0);
    }

    const int lh = lane >> 4, lm = lane & 15;
#pragma unroll
    for (int i = 0; i < 4; i++) {
        const int row0 = bm + wr * 64 + i * 16 + lh * 4;
#pragma unroll
        for (int jf = 0; jf < 4; jf++) {
            const int col = bn + wc * 64 + jf * 16 + lm;
            const float bval = bias[col];
#pragma unroll
            for (int r = 0; r < 4; r++) {
                const int row = row0 + r;
                const size_t idx = (size_t)row * N + col;
                float v = acc[i][jf][r] + bval;
                if (OP == 0) {
                    outb[idx] = (bf16)v;
                } else if (OP == 1) {
                    v += resid[idx];
                    outf[idx] = v;
                    float hh = gamma[col] * tanhf(v * alpha_p[0]) + beta[col];
                    outb[idx] = (bf16)hh;
                } else if (OP == 2) {
                    float g = 0.5f * v * (1.0f + erff(v * 0.70710678118f));
                    outb[idx] = (bf16)g;
                } else {
                    v += resid[idx];
                    outf[idx] = v;
                }
            }
        }
    }
}

// ---------------- causal flash attention, H=16 D=64 T=2048 -------------------
// Swapped QK^T: S^T = mfma(K, Q) so each lane owns one q-row (q = lane&15);
// softmax reduce = in-lane + 2 shfl_xor. V double-buffered in LDS, transposed
// with XOR-swizzled 8-blocks (write b64, read b128). One barrier per KV tile.
__global__ void attn_kernel(const bf16* __restrict__ qkv, bf16* __restrict__ out) {
    const int bq = blockIdx.x;          // q tile (64 rows)
    const int bh = blockIdx.y;          // b*16 + h
    const int b = bh >> 4, h = bh & 15;
    const int tid = threadIdx.x, lane = tid & 63, w = tid >> 6;
    const int T = 2048;
    const size_t C3 = 3072;
    const bf16* qb = qkv + (size_t)b * T * C3 + h * 64;
    const bf16* kb = qb + 1024;
    const bf16* vb = qb + 2048;

    __shared__ bf16 Vt[2][64][72];      // [buf][d][k-swizzled]
    __shared__ bf16 Pl[4][16][72];      // per-wave P [q][k]

    const int q0w = bq * 64 + w * 16;
    const int lm = lane & 15;
    const int lh = lane >> 4;

    bf16x8 qf0, qf1;
    {
        size_t qoff = (size_t)(q0w + lm) * C3 + lh * 8;
        qf0 = *(const bf16x8*)&qb[qoff];
        qf1 = *(const bf16x8*)&qb[qoff + 32];
    }
    f32x4 acc[4] = {};                  // O[q=lh*4+r][d=df*16+lm]
    float mS = -1e30f, lS = 0.f;        // stats for q = q0w+lm (replicated x4)

    const int nt = bq + 1;
    const int sg = tid & 7;             // d-group (8 rows of Vt)
    const int sq = tid >> 3;            // k-quad, valid 0..15 for tid<128

    auto stage = [&](int buf, int k0) {
        if (tid < 128) {
            bf16x8 rv[4];
#pragma unroll
            for (int i = 0; i < 4; ++i)
                rv[i] = *(const bf16x8*)&vb[(size_t)(k0 + sq * 4 + i) * C3 + sg * 8];
            const int cbase = ((((sq >> 1) ^ sg) & 7) << 3) + ((sq & 1) << 2);
#pragma unroll
            for (int e = 0; e < 8; ++e) {
                bf16x4 wv;
                wv[0] = rv[0][e]; wv[1] = rv[1][e]; wv[2] = rv[2][e]; wv[3] = rv[3][e];
                *(bf16x4*)&Vt[buf][sg * 8 + e][cbase] = wv;
            }
        }
    };

    stage(0, 0);
    __syncthreads();

    for (int kt = 0; kt < nt; ++kt) {
        const int k0 = kt * 64;
        const int buf = kt & 1;
        if (kt + 1 < nt) stage(buf ^ 1, k0 + 64);

        // S^T fragments: s[f][r] = S[k0+f*16+lh*4+r][q0w+lm]
        f32x4 s[4];
#pragma unroll
        for (int f = 0; f < 4; ++f) {
            size_t kg = (size_t)(k0 + f * 16 + lm) * C3 + lh * 8;
            bf16x8 kf0 = *(const bf16x8*)&kb[kg];
            bf16x8 kf1 = *(const bf16x8*)&kb[kg + 32];
            f32x4 z = {};
            z = __builtin_amdgcn_mfma_f32_16x16x32_bf16(kf0, qf0, z, 0, 0, 0);
            z = __builtin_amdgcn_mfma_f32_16x16x32_bf16(kf1, qf1, z, 0, 0, 0);
            s[f] = z;
        }
        const int qg = q0w + lm;
        if (kt == bq) {
#pragma unroll
            for (int f = 0; f < 4; ++f)
#pragma unroll
                for (int r = 0; r < 4; ++r) {
                    const int kgl = k0 + f * 16 + lh * 4 + r;
                    float v = s[f][r] * 0.125f;
                    s[f][r] = (kgl > qg) ? -1e30f : v;
                }
        } else {
#pragma unroll
            for (int f = 0; f < 4; ++f)
#pragma unroll
                for (int r = 0; r < 4; ++r) s[f][r] *= 0.125f;
        }

        // online softmax for row q = qg (in-lane + 2 shfl)
        float m0 = fmaxf(fmaxf(s[0][0], s[0][1]), fmaxf(s[0][2], s[0][3]));
        float m1 = fmaxf(fmaxf(s[1][0], s[1][1]), fmaxf(s[1][2], s[1][3]));
        float m2 = fmaxf(fmaxf(s[2][0], s[2][1]), fmaxf(s[2][2], s[2][3]));
        float m3 = fmaxf(fmaxf(s[3][0], s[3][1]), fmaxf(s[3][2], s[3][3]));
        float pm = fmaxf(fmaxf(m0, m1), fmaxf(m2, m3));
        pm = fmaxf(pm, __shfl_xor(pm, 16));
        pm = fmaxf(pm, __shfl_xor(pm, 32));
        const float mnew = fmaxf(mS, pm);
        const float corr = __expf(mS - mnew);
        mS = mnew;

        float rs = 0.f;
#pragma unroll
        for (int f = 0; f < 4; ++f) {
            bf16x4 pw;
#pragma unroll
            for (int r = 0; r < 4; ++r) {
                const float pv = __expf(s[f][r] - mnew);
                rs += pv;
                pw[r] = (bf16)pv;
            }
            *(bf16x4*)&Pl[w][lm][f * 16 + lh * 4] = pw;
        }
        rs += __shfl_xor(rs, 16);
        rs += __shfl_xor(rs, 32);
        lS = lS * corr + rs;

        // redistribute corr to acc layout (q = lh*4+r)
        float cq[4];
#pragma unroll
        for (int r = 0; r < 4; ++r) cq[r] = __shfl(corr, lh * 4 + r);
#pragma unroll
        for (int df = 0; df < 4; ++df)
#pragma unroll
            for (int r = 0; r < 4; ++r) acc[df][r] *= cq[r];

        // PV: O += P @ V
#pragma unroll
        for (int kk = 0; kk < 2; ++kk) {
            bf16x8 pa = *(const bf16x8*)&Pl[w][lm][kk * 32 + lh * 8];
            const int kblk = 4 * kk + lh;
#pragma unroll
            for (int df = 0; df < 4; ++df) {
                const int dr = df * 16 + lm;
                bf16x8 vf = *(const bf16x8*)&Vt[buf][dr][((kblk ^ ((dr >> 3) & 7)) << 3)];
                acc[df] = __builtin_amdgcn_mfma_f32_16x16x32_bf16(pa, vf, acc[df], 0, 0, 0);
            }
        }
        __syncthreads();
    }

    // epilogue
    const float linv = 1.0f / lS;
    float iq[4];
#pragma unroll
    for (int r = 0; r < 4; ++r) iq[r] = __shfl(linv, lh * 4 + r);
    bf16* ob = out + (size_t)b * T * 1024 + h * 64;
#pragma unroll
    for (int r = 0; r < 4; ++r) {
        const int q = q0w + lh * 4 + r;
#pragma unroll
        for (int df = 0; df < 4; ++df)
            ob[(size_t)q * 1024 + df * 16 + lm] = (bf16)(acc[df][r] * iq[r]);
    }
}

// -----------------------------------------------------------------------------
extern "C" void kernel_launch(void* const* d_in, const int* in_sizes, int n_in,
                              void* d_out, int out_size, void* d_ws, size_t ws_size,
                              hipStream_t stream) {
    const float* x      = (const float*)d_in[0];
    const float* alpha  = (const float*)d_in[1];
    const float* gamma  = (const float*)d_in[2];
    const float* beta   = (const float*)d_in[3];
    const float* w_attn = (const float*)d_in[4];
    const float* b_attn = (const float*)d_in[5];
    const float* w_proj = (const float*)d_in[6];
    const float* b_proj = (const float*)d_in[7];
    const float* w_fc   = (const float*)d_in[8];
    const float* b_fc   = (const float*)d_in[9];
    const float* w_fc2  = (const float*)d_in[10];
    const float* b_fc2  = (const float*)d_in[11];
    float* out = (float*)d_out;

    const int M = 4096, C = 1024, F = 4096;
    char* ws = (char*)d_ws;
    bf16* wt_attn = (bf16*)ws;                        // [3C][C]   6 MB
    bf16* wt_proj = wt_attn + (size_t)3 * C * C;      // [C][C]    2 MB
    bf16* wt_fc   = wt_proj + (size_t)C * C;          // [F][C]    8 MB
    bf16* wt_fc2  = wt_fc   + (size_t)F * C;          // [C][F]    8 MB
    bf16* hbuf    = wt_fc2  + (size_t)C * F;          // [M][C]    8 MB (h, then h2)
    bf16* qkvbuf  = hbuf    + (size_t)M * C;          // [M][3C] then act [M][F] 32 MB
    bf16* aout    = qkvbuf  + (size_t)M * F;          // [M][C]    8 MB
    float* x2     = (float*)(aout + (size_t)M * C);   // [M][C]   16 MB

    dim3 blk(256);
    conv_t_kernel<<<dim3(3 * C / 64, C / 64), blk, 0, stream>>>(w_attn, wt_attn, C, 3 * C);
    conv_t_kernel<<<dim3(C / 64, C / 64),     blk, 0, stream>>>(w_proj, wt_proj, C, C);
    conv_t_kernel<<<dim3(F / 64, C / 64),     blk, 0, stream>>>(w_fc,   wt_fc,   C, F);
    conv_t_kernel<<<dim3(C / 64, F / 64),     blk, 0, stream>>>(w_fc2,  wt_fc2,  F, C);

    dyt_kernel<<<dim3(M * C / 1024), blk, 0, stream>>>(x, alpha, gamma, beta, hbuf, M * C);

    // QKV: [M][3C] = h @ w_attn
    gemm_kernel<0><<<dim3(3 * C / 128, M / 128), blk, 0, stream>>>(
        hbuf, wt_attn, b_attn, nullptr, nullptr, qkvbuf, nullptr, nullptr, nullptr, M, 3 * C, C);

    attn_kernel<<<dim3(32, 32), blk, 0, stream>>>(qkvbuf, aout);

    // proj + residual(x) -> x2 (f32) and h2 = DyT(x2) (bf16, into hbuf)
    gemm_kernel<1><<<dim3(C / 128, M / 128), blk, 0, stream>>>(
        aout, wt_proj, b_proj, x, x2, hbuf, alpha, gamma, beta, M, C, C);

    // fc + gelu -> act (reuse qkvbuf region, [M][F])
    gemm_kernel<2><<<dim3(F / 128, M / 128), blk, 0, stream>>>(
        hbuf, wt_fc, b_fc, nullptr, nullptr, qkvbuf, nullptr, nullptr, nullptr, M, F, C);

    // fc2 + residual(x2) -> d_out (f32)
    gemm_kernel<3><<<dim3(C / 128, M / 128), blk, 0, stream>>>(
        qkvbuf, wt_fc2, b_fc2, x2, out, nullptr, nullptr, nullptr, nullptr, M, C, F);
}